// Round 1
// baseline (1118.175 us; speedup 1.0000x reference)
//
#include <hip/hip_runtime.h>

typedef __attribute__((ext_vector_type(8))) short short8;
typedef __attribute__((ext_vector_type(4))) float f32x4;
typedef unsigned short u16;
typedef unsigned int u32;

#define NB   16
#define NLQ  2048
#define NLK  2048
#define NH   1024

// ---------------- helpers ----------------
__device__ __forceinline__ u16 f2bf(float x){
  u32 u = __float_as_uint(x);
  return (u16)((u + 0x7fffu + ((u >> 16) & 1u)) >> 16);
}
__device__ __forceinline__ float bf2f(u16 h){ return __uint_as_float(((u32)h) << 16); }

__device__ __forceinline__ void split_bf(float x, u16& hi, u16& lo){
  u16 h = f2bf(x);
  float r = x - bf2f(h);
  hi = h; lo = f2bf(r);
}

typedef const __attribute__((address_space(1))) void* gas_ptr;
typedef __attribute__((address_space(3))) void* las_ptr;

__device__ __forceinline__ void gll16(const void* g, void* l){
  __builtin_amdgcn_global_load_lds((gas_ptr)g, (las_ptr)l, 16, 0, 0);
}

// stage 128x32 bf16 tile (row-major, ld in elems) -> LDS linear [128][32]
__device__ __forceinline__ void stage_bf(const u16* __restrict__ src, int ld, u16* lds){
  const int lane = threadIdx.x & 63, wid = threadIdx.x >> 6;
#pragma unroll
  for (int t = 0; t < 2; ++t){
    int ub = t*256 + wid*64;     // wave-uniform 16B-unit base
    int u  = ub + lane;
    int r  = u >> 2;             // row 0..127
    int c  = (u & 3) << 3;       // col elem (x8 bf16)
    gll16(src + (size_t)r*ld + c, lds + (size_t)ub*8);
  }
}

// stage 128x32 fp32 tile with 16B-slot XOR swizzle (slot ^= row&7)
__device__ __forceinline__ void stage_f32_swz(const float* __restrict__ src, int ld, float* lds){
  const int lane = threadIdx.x & 63, wid = threadIdx.x >> 6;
#pragma unroll
  for (int t = 0; t < 4; ++t){
    int ub = t*256 + wid*64;
    int u  = ub + lane;
    int r  = u >> 3;                    // row 0..127 (8 slots of 16B per row)
    int s  = (u & 7) ^ (r & 7);         // pre-swizzled source slot
    gll16(src + (size_t)r*ld + s*4, lds + (size_t)ub*4);
  }
}

__device__ __forceinline__ short8 frag_bf(const u16* lds, int row, int fg){
  return *(const short8*)(lds + (size_t)row*32 + fg*8);
}

// read 8 fp32 from swizzled [128][32] f32 tile, convert to bf16 frag
__device__ __forceinline__ short8 frag_f32(const float* lds, int row, int fg){
  int c0 = fg*2;
  const f32x4* p4 = (const f32x4*)lds;
  f32x4 x = p4[(size_t)row*8 + (c0 ^ (row & 7))];
  f32x4 y = p4[(size_t)row*8 + ((c0+1) ^ (row & 7))];
  short8 r;
  r[0]=(short)f2bf(x[0]); r[1]=(short)f2bf(x[1]); r[2]=(short)f2bf(x[2]); r[3]=(short)f2bf(x[3]);
  r[4]=(short)f2bf(y[0]); r[5]=(short)f2bf(y[1]); r[6]=(short)f2bf(y[2]); r[7]=(short)f2bf(y[3]);
  return r;
}

#define MFMA16(a,b,c) __builtin_amdgcn_mfma_f32_16x16x32_bf16((a),(b),(c),0,0,0)

__device__ __forceinline__ float wredmax(float v){
#pragma unroll
  for (int off = 32; off > 0; off >>= 1) v = fmaxf(v, __shfl_xor(v, off, 64));
  return v;
}
__device__ __forceinline__ float wredsum(float v){
#pragma unroll
  for (int off = 32; off > 0; off >>= 1) v += __shfl_xor(v, off, 64);
  return v;
}

// ---------------- converts ----------------
// Q [B,LQ,H] f32 -> CB[:, :, 1024:2048] = Qhi (row stride 2048), Qlo [B,LQ,H]
__global__ void conv_q(const float* __restrict__ Q, u16* __restrict__ CB, u16* __restrict__ Qlo){
  size_t i = (size_t)blockIdx.x*256 + threadIdx.x;  // quad id, total 8388608
  float4 v = ((const float4*)Q)[i];
  size_t e = i*4;
  size_t row = e >> 10;        // b*2048+q
  int h = (int)(e & 1023);
  u16 h0,h1,h2,h3,l0,l1,l2,l3;
  split_bf(v.x,h0,l0); split_bf(v.y,h1,l1); split_bf(v.z,h2,l2); split_bf(v.w,h3,l3);
  ushort4 hv; hv.x=h0; hv.y=h1; hv.z=h2; hv.w=h3;
  ushort4 lv; lv.x=l0; lv.y=l1; lv.z=l2; lv.w=l3;
  *(ushort4*)(CB + row*2048 + 1024 + h) = hv;
  *(ushort4*)(Qlo + row*1024 + h) = lv;
}

// C [B,LK,H] f32 -> Chi,Clo [B,LK,H] bf16 ; CT [B,H,LK] bf16 (hi only)
__global__ void conv_c(const float* __restrict__ C, u16* __restrict__ Chi,
                       u16* __restrict__ Clo, u16* __restrict__ CT){
  __shared__ u16 tile[64][65];
  const int b = blockIdx.z;
  const int k0 = blockIdx.y*64, h0 = blockIdx.x*64;
  const float* Cb = C + ((size_t)b*NLK + k0)*NH + h0;
  const int t = threadIdx.x;
#pragma unroll
  for (int i = 0; i < 4; ++i){
    int q = i*256 + t;          // 0..1023 quads
    int r = q >> 4;             // k-local 0..63
    int c4 = (q & 15) * 4;      // h-local
    float4 v = *(const float4*)(Cb + (size_t)r*NH + c4);
    u16 h0_,h1_,h2_,h3_,l0_,l1_,l2_,l3_;
    split_bf(v.x,h0_,l0_); split_bf(v.y,h1_,l1_); split_bf(v.z,h2_,l2_); split_bf(v.w,h3_,l3_);
    size_t base = ((size_t)b*NLK + k0 + r)*NH + h0 + c4;
    ushort4 hv; hv.x=h0_; hv.y=h1_; hv.z=h2_; hv.w=h3_;
    ushort4 lv; lv.x=l0_; lv.y=l1_; lv.z=l2_; lv.w=l3_;
    *(ushort4*)(Chi + base) = hv;
    *(ushort4*)(Clo + base) = lv;
    tile[r][c4+0]=h0_; tile[r][c4+1]=h1_; tile[r][c4+2]=h2_; tile[r][c4+3]=h3_;
  }
  __syncthreads();
#pragma unroll
  for (int i = 0; i < 4; ++i){
    int q = i*256 + t;
    int hl = q >> 4;            // h-local
    int k4 = (q & 15) * 4;      // k-local
    ushort4 o;
    o.x = tile[k4+0][hl]; o.y = tile[k4+1][hl]; o.z = tile[k4+2][hl]; o.w = tile[k4+3][hl];
    *(ushort4*)(CT + ((size_t)b*NH + h0 + hl)*NLK + k0 + k4) = o;
  }
}

// W [H,2H] f32 -> bf16
__global__ void conv_w(const float* __restrict__ W, u16* __restrict__ Wbf){
  size_t i = (size_t)blockIdx.x*256 + threadIdx.x;  // quads, total 524288
  float4 v = ((const float4*)W)[i];
  ushort4 hv; hv.x=f2bf(v.x); hv.y=f2bf(v.y); hv.z=f2bf(v.z); hv.w=f2bf(v.w);
  *(ushort4*)(Wbf + i*4) = hv;
}

// ---------------- K1: S = Q . C^T  (bf16 hi/lo split, 3 MFMA) ----------------
__global__ __launch_bounds__(256,2) void k1_scores(
    const u16* __restrict__ Qhi, const u16* __restrict__ Qlo,
    const u16* __restrict__ Chi, const u16* __restrict__ Clo,
    float* __restrict__ S)
{
  __shared__ __align__(16) u16 sAh[4096], sAl[4096], sBh[4096], sBl[4096];
  const int b = blockIdx.z;
  const int brow = blockIdx.y*128, bcol = blockIdx.x*128;
  const u16* Ah = Qhi + (size_t)b*4194304 + (size_t)brow*2048;  // CB upper half, ld 2048
  const u16* Al = Qlo + (size_t)b*2097152 + (size_t)brow*1024;
  const u16* Bh = Chi + (size_t)b*2097152 + (size_t)bcol*1024;
  const u16* Bl = Clo + (size_t)b*2097152 + (size_t)bcol*1024;
  const int lane = threadIdx.x & 63, wid = threadIdx.x >> 6;
  const int wr = wid >> 1, wc = wid & 1;
  const int fr = lane & 15, fg = lane >> 4;
  f32x4 zero = {0.f,0.f,0.f,0.f};
  f32x4 acc[4][4];
#pragma unroll
  for (int m=0;m<4;++m)
#pragma unroll
    for (int n=0;n<4;++n) acc[m][n] = zero;

  for (int k0 = 0; k0 < 1024; k0 += 32){
    __syncthreads();
    stage_bf(Ah + k0, 2048, sAh);
    stage_bf(Al + k0, 1024, sAl);
    stage_bf(Bh + k0, 1024, sBh);
    stage_bf(Bl + k0, 1024, sBl);
    __syncthreads();
    short8 a[4], al[4], bh[4], bl[4];
#pragma unroll
    for (int m=0;m<4;++m){
      int r = wr*64 + m*16 + fr;
      a[m]  = frag_bf(sAh, r, fg);
      al[m] = frag_bf(sAl, r, fg);
    }
#pragma unroll
    for (int n=0;n<4;++n){
      int r = wc*64 + n*16 + fr;
      bh[n] = frag_bf(sBh, r, fg);
      bl[n] = frag_bf(sBl, r, fg);
    }
#pragma unroll
    for (int m=0;m<4;++m)
#pragma unroll
      for (int n=0;n<4;++n){
        acc[m][n] = MFMA16(a[m],  bh[n], acc[m][n]);
        acc[m][n] = MFMA16(a[m],  bl[n], acc[m][n]);
        acc[m][n] = MFMA16(al[m], bh[n], acc[m][n]);
      }
  }
  float* Sb = S + (size_t)b*4194304;
#pragma unroll
  for (int m=0;m<4;++m)
#pragma unroll
    for (int n=0;n<4;++n){
      int col  = bcol + wc*64 + n*16 + fr;
      int rowb = brow + wr*64 + m*16 + fg*4;
#pragma unroll
      for (int r4=0;r4<4;++r4)
        Sb[(size_t)(rowb + r4)*2048 + col] = acc[m][n][r4];
    }
}

// ---------------- K2: in-place masked row softmax ----------------
__global__ __launch_bounds__(256) void softmax_rows(float* __restrict__ S, const void* __restrict__ maskp){
  __shared__ float red[4];
  __shared__ int s_is8;
  const int row = blockIdx.x;
  const int b = row >> 11;
  const int t = threadIdx.x;
  if (t == 0){
    const u32* mw0 = (const u32*)maskp;
    u32 accu = 0;
#pragma unroll
    for (int i = 0; i < 32; ++i) accu |= mw0[i];
    s_is8 = (accu & 0xffffff00u) ? 1 : 0;   // byte-packed bools if high bytes populated
  }
  float* Sr = S + (size_t)row * 2048;
  float4 s0 = ((const float4*)Sr)[t];
  float4 s1 = ((const float4*)Sr)[t + 256];
  __syncthreads();
  const int is8 = s_is8;
  float v[8] = {s0.x,s0.y,s0.z,s0.w, s1.x,s1.y,s1.z,s1.w};
  const unsigned char* mb = (const unsigned char*)maskp + (size_t)b*2048;
  const int* mw = (const int*)maskp + (size_t)b*2048;
  const int kb0 = t*4, kb1 = t*4 + 1024;
  const float NINF = -__builtin_inff();
#pragma unroll
  for (int j=0;j<4;++j){
    int m0 = is8 ? (int)mb[kb0+j] : mw[kb0+j];
    int m1 = is8 ? (int)mb[kb1+j] : mw[kb1+j];
    if (m0) v[j]   = NINF;
    if (m1) v[4+j] = NINF;
  }
  float m = v[0];
#pragma unroll
  for (int j=1;j<8;++j) m = fmaxf(m, v[j]);
  m = wredmax(m);
  if ((t & 63) == 0) red[t>>6] = m;
  __syncthreads();
  float M = fmaxf(fmaxf(red[0],red[1]), fmaxf(red[2],red[3]));
  __syncthreads();
  float e[8]; float sum = 0.f;
#pragma unroll
  for (int j=0;j<8;++j){ e[j] = __expf(v[j]-M); sum += e[j]; }
  sum = wredsum(sum);
  if ((t & 63) == 0) red[t>>6] = sum;
  __syncthreads();
  float L = red[0]+red[1]+red[2]+red[3];
  float inv = 1.0f / L;
  float4 o0 = {e[0]*inv, e[1]*inv, e[2]*inv, e[3]*inv};
  float4 o1 = {e[4]*inv, e[5]*inv, e[6]*inv, e[7]*inv};
  ((float4*)Sr)[t] = o0;
  ((float4*)Sr)[t+256] = o1;
}

// ---------------- K3: mix = P . CT^T -> bf16 into CB[:, :, 0:1024] ----------------
__global__ __launch_bounds__(256,2) void k3_mix(
    const float* __restrict__ P, const u16* __restrict__ CT, u16* __restrict__ CB)
{
  __shared__ __align__(16) float sA[4096];
  __shared__ __align__(16) u16 sB[4096];
  const int b = blockIdx.z;
  const int brow = blockIdx.y*128, bcol = blockIdx.x*128;  // bcol over H
  const float* Ap = P  + (size_t)b*4194304 + (size_t)brow*2048;
  const u16*   Bp = CT + (size_t)b*2097152 + (size_t)bcol*2048;
  const int lane = threadIdx.x & 63, wid = threadIdx.x >> 6;
  const int wr = wid >> 1, wc = wid & 1;
  const int fr = lane & 15, fg = lane >> 4;
  f32x4 zero = {0.f,0.f,0.f,0.f};
  f32x4 acc[4][4];
#pragma unroll
  for (int m=0;m<4;++m)
#pragma unroll
    for (int n=0;n<4;++n) acc[m][n] = zero;

  for (int k0 = 0; k0 < 2048; k0 += 32){
    __syncthreads();
    stage_f32_swz(Ap + k0, 2048, sA);
    stage_bf(Bp + k0, 2048, sB);
    __syncthreads();
    short8 a[4], bb[4];
#pragma unroll
    for (int m=0;m<4;++m) a[m] = frag_f32(sA, wr*64 + m*16 + fr, fg);
#pragma unroll
    for (int n=0;n<4;++n) bb[n] = frag_bf(sB, wc*64 + n*16 + fr, fg);
#pragma unroll
    for (int m=0;m<4;++m)
#pragma unroll
      for (int n=0;n<4;++n)
        acc[m][n] = MFMA16(a[m], bb[n], acc[m][n]);
  }
  u16* Ob = CB + (size_t)b*4194304;
#pragma unroll
  for (int m=0;m<4;++m)
#pragma unroll
    for (int n=0;n<4;++n){
      int col  = bcol + wc*64 + n*16 + fr;       // < 1024
      int rowb = brow + wr*64 + m*16 + fg*4;
#pragma unroll
      for (int r4=0;r4<4;++r4)
        Ob[(size_t)(rowb + r4)*2048 + col] = f2bf(acc[m][n][r4]);
    }
}

// ---------------- K4: out = tanh(CB . W^T + b) ----------------
__global__ __launch_bounds__(256,2) void k4_out(
    const u16* __restrict__ CB, const u16* __restrict__ Wbf,
    const float* __restrict__ bias, float* __restrict__ Out)
{
  __shared__ __align__(16) u16 sA[4096], sB[4096];
  const int b = blockIdx.z;
  const int brow = blockIdx.y*128, bcol = blockIdx.x*128;  // bcol over H out
  const u16* Ap = CB  + (size_t)b*4194304 + (size_t)brow*2048;
  const u16* Bp = Wbf + (size_t)bcol*2048;
  const int lane = threadIdx.x & 63, wid = threadIdx.x >> 6;
  const int wr = wid >> 1, wc = wid & 1;
  const int fr = lane & 15, fg = lane >> 6 ? 0 : 0, fgr = lane >> 4;
  f32x4 zero = {0.f,0.f,0.f,0.f};
  f32x4 acc[4][4];
#pragma unroll
  for (int m=0;m<4;++m)
#pragma unroll
    for (int n=0;n<4;++n) acc[m][n] = zero;
  (void)fg;

  for (int k0 = 0; k0 < 2048; k0 += 32){
    __syncthreads();
    stage_bf(Ap + k0, 2048, sA);
    stage_bf(Bp + k0, 2048, sB);
    __syncthreads();
    short8 a[4], bb[4];
#pragma unroll
    for (int m=0;m<4;++m) a[m] = frag_bf(sA, wr*64 + m*16 + fr, fgr);
#pragma unroll
    for (int n=0;n<4;++n) bb[n] = frag_bf(sB, wc*64 + n*16 + fr, fgr);
#pragma unroll
    for (int m=0;m<4;++m)
#pragma unroll
      for (int n=0;n<4;++n)
        acc[m][n] = MFMA16(a[m], bb[n], acc[m][n]);
  }
  float* Ob = Out + (size_t)b*2097152;
#pragma unroll
  for (int m=0;m<4;++m)
#pragma unroll
    for (int n=0;n<4;++n){
      int col  = bcol + wc*64 + n*16 + fr;
      float bv = bias[col];
      int rowb = brow + wr*64 + m*16 + fgr*4;
#pragma unroll
      for (int r4=0;r4<4;++r4)
        Ob[(size_t)(rowb + r4)*1024 + col] = tanhf(acc[m][n][r4] + bv);
    }
}

// ---------------- launch ----------------
extern "C" void kernel_launch(void* const* d_in, const int* in_sizes, int n_in,
                              void* d_out, int out_size, void* d_ws, size_t ws_size,
                              hipStream_t stream) {
  (void)in_sizes; (void)n_in; (void)out_size;
  const float* Q    = (const float*)d_in[0];
  const float* C    = (const float*)d_in[1];
  const void*  mask = d_in[2];
  const float* W    = (const float*)d_in[3];
  const float* bias = (const float*)d_in[4];
  float* out_f = (float*)d_out;

  // ws layout (bytes): CB 134217728 | Qlo 67108864 | CT 67108864 | Wbf 4194304
  if (ws_size < 272629760ull) return;  // insufficient scratch -> bail (visible as validation failure)
  u16* CB  = (u16*)d_ws;
  u16* Qlo = (u16*)((char*)d_ws + 134217728);
  u16* CT  = (u16*)((char*)d_ws + 201326592);
  u16* Wbf = (u16*)((char*)d_ws + 268435456);

  // d_out out-region doubles as scratch for Chi/Clo (dead before K4 writes it)
  u16* Chi = (u16*)d_out;
  u16* Clo = Chi + 33554432;
  float* S = out_f + 33554432;   // attn region: raw scores -> probs in place

  conv_q<<<32768, 256, 0, stream>>>(Q, CB, Qlo);
  conv_c<<<dim3(16,32,16), 256, 0, stream>>>(C, Chi, Clo, CT);
  conv_w<<<2048, 256, 0, stream>>>(W, Wbf);
  k1_scores<<<dim3(16,16,16), 256, 0, stream>>>(CB + 1024, Qlo, Chi, Clo, S);
  softmax_rows<<<32768, 256, 0, stream>>>(S, mask);
  k3_mix<<<dim3(8,16,16), 256, 0, stream>>>(S, CT, CB);
  k4_out<<<dim3(8,16,16), 256, 0, stream>>>(CB, Wbf, bias, out_f);
}